// Round 2
// baseline (355.874 us; speedup 1.0000x reference)
//
#include <hip/hip_runtime.h>

// Problem constants (match reference setup_inputs)
#define BB 16
#define TT 32641
#define EE 128
#define LL (TT + EE - 1)             // 32768 = 2^15 groups
#define RT 32                        // rows per tile (16 KB LDS)
#define NTILES ((TT + RT - 1) / RT)  // 1021 tiles per batch
#define GPT (RT + EE - 1)            // 159 group partials per tile
#define SLOT 160                     // stride: 159 G-partials + 1 Qw slot
#define NTH 256
#define CHUNK 8                      // tiles per block (pipelined)
#define NCHUNK ((NTILES + CHUNK - 1) / CHUNK)  // 128
#define P2_BLOCKS 256

typedef float vf4 __attribute__((ext_vector_type(4)));

// c(t) = |{(i,j): i+j==t, 0<=i<TT, 0<=j<EE}|  (TT >= EE)
__device__ __forceinline__ float groupWeight(int t) {
    int c = min(min(t + 1, EE), LL - t);
    return 1.0f / (float)c;
}

// Raw barrier that does NOT drain vmcnt (unlike __syncthreads, which the
// compiler lowers to s_waitcnt vmcnt(0) lgkmcnt(0) + s_barrier). lgkmcnt(0)
// first so this wave's LDS writes/reads are complete before crossing; the
// "memory" clobber pins compiler ordering of LDS accesses around it.
#define LGKM_BARRIER() asm volatile("s_waitcnt lgkmcnt(0)\n\ts_barrier" ::: "memory")

// Issue nontemporal float4 loads for tile `ktile` into r0..r3 (guarded for
// the single partial tail tile, k = NTILES-1, nrows = 1).
#define ISSUE_LOADS(ktile)                                                         \
    do {                                                                           \
        const int _rr = (ktile) * RT;                                              \
        const vf4* __restrict__ _src = (const vf4*)(inb + (size_t)_rr * EE);       \
        const int _nvec = min(RT, TT - _rr) * (EE / 4);                            \
        if (_nvec == RT * (EE / 4)) {                                              \
            r0 = __builtin_nontemporal_load(&_src[tid + 0 * NTH]);                 \
            r1 = __builtin_nontemporal_load(&_src[tid + 1 * NTH]);                 \
            r2 = __builtin_nontemporal_load(&_src[tid + 2 * NTH]);                 \
            r3 = __builtin_nontemporal_load(&_src[tid + 3 * NTH]);                 \
        } else {                                                                   \
            if (tid + 0 * NTH < _nvec) r0 = __builtin_nontemporal_load(&_src[tid + 0 * NTH]); \
            if (tid + 1 * NTH < _nvec) r1 = __builtin_nontemporal_load(&_src[tid + 1 * NTH]); \
            if (tid + 2 * NTH < _nvec) r2 = __builtin_nontemporal_load(&_src[tid + 2 * NTH]); \
            if (tid + 3 * NTH < _nvec) r3 = __builtin_nontemporal_load(&_src[tid + 3 * NTH]); \
        }                                                                          \
    } while (0)

// Pass 1, pipelined: each block owns CHUNK consecutive tiles of one batch.
// Steady state per tile: regs->LDS (counted vmcnt waits only), raw barrier,
// issue next tile's loads (HBM latency hides under Phase B), diagonal
// compute, raw barrier. vmcnt is never drained to 0 inside the loop.
__global__ __launch_bounds__(NTH, 8) void tc_pass1(const float* __restrict__ in,
                                                   float* __restrict__ part) {
    __shared__ float lsum[RT * EE];        // 16 KB, single buffer
    __shared__ float red[NTH / 64];
    const int tid = threadIdx.x;
    const int c   = (NCHUNK - 1) - blockIdx.x;   // reversed chunk order (R7)
    const int b   = (BB - 1) - blockIdx.y;       // reversed batch order (R7)
    const int k0  = c * CHUNK;
    const int ntile = min(CHUNK, NTILES - k0);

    vf4* __restrict__ ldst = (vf4*)lsum;
    const float* __restrict__ inb = in + (size_t)b * TT * EE;

    vf4 r0 = {0.f, 0.f, 0.f, 0.f}, r1 = r0, r2 = r0, r3 = r0;

    // prologue: issue loads for the first tile
    ISSUE_LOADS(k0);

    for (int t = 0; t < ntile; ++t) {
        const int k     = k0 + t;
        const int rrow  = k * RT;
        const int nrows = min(RT, TT - rrow);
        const int nvec  = nrows * (EE / 4);

        // staged regs -> LDS; compiler inserts counted s_waitcnt vmcnt(N)
        // per register, so newer prefetch loads stay in flight.
        if (nvec == RT * (EE / 4)) {
            ldst[tid + 0 * NTH] = r0;
            ldst[tid + 1 * NTH] = r1;
            ldst[tid + 2 * NTH] = r2;
            ldst[tid + 3 * NTH] = r3;
        } else {
            if (tid + 0 * NTH < nvec) ldst[tid + 0 * NTH] = r0;
            if (tid + 1 * NTH < nvec) ldst[tid + 1 * NTH] = r1;
            if (tid + 2 * NTH < nvec) ldst[tid + 2 * NTH] = r2;
            if (tid + 3 * NTH < nvec) ldst[tid + 3 * NTH] = r3;
        }
        LGKM_BARRIER();   // tile visible to all waves; vmcnt NOT drained

        // issue next tile's loads now: their latency hides under Phase B.
        // sched_barrier(0) pins the loads HERE — hipcc must not sink them
        // down to their use (next iteration's LDS writes), which would
        // silently destroy the overlap.
        if (t + 1 < ntile) {
            ISSUE_LOADS(k + 1);
            __builtin_amdgcn_sched_barrier(0);
        }

        // Phase B: lane d walks anti-diagonal d: lsum[i*EE + (d-i)],
        // consecutive lanes -> consecutive LDS addresses -> conflict-free.
        float* __restrict__ base = part + ((size_t)b * NTILES + k) * SLOT;
        float qw = 0.0f;
        if (tid < GPT) {
            const int d   = tid;
            const int ilo = max(0, d - (EE - 1));
            const int ihi = min(nrows - 1, d);
            float g = 0.0f, q = 0.0f;
            for (int i = ilo; i <= ihi; ++i) {
                float x = lsum[i * EE + (d - i)];
                g += x;
                q += x * x;
            }
            base[d] = g;                       // zero when loop empty
            if (ihi >= ilo) qw = q * groupWeight(rrow + d);  // NaN guard for t >= LL
        }

        // block-reduce qw -> slot GPT (non-atomic)
        #pragma unroll
        for (int o = 32; o > 0; o >>= 1) qw += __shfl_down(qw, o, 64);
        if ((tid & 63) == 0) red[tid >> 6] = qw;
        // Doubles as "all lsum reads done" barrier: each wave's qw depends on
        // its ds_reads, and lgkmcnt(0) runs before s_barrier.
        LGKM_BARRIER();
        if (tid == 0) base[GPT] = red[0] + red[1] + red[2] + red[3];
        // tid 0's red[] read is ordered before the NEXT iteration's red[]
        // writes by the post-write barrier at the top of the next iteration.
    }
}

// Pass 2: S1 = sum over (b,t) of (G(b,t)*w(t))^2 from <=5 tile partials;
//         S2 = sum of per-tile w*q slots. Non-atomic block partials.
__global__ __launch_bounds__(NTH) void tc_pass2(const float* __restrict__ part,
                                                float* __restrict__ part2) {
    __shared__ float redA[NTH / 64], redB[NTH / 64];
    float s1 = 0.0f, s2 = 0.0f;
    const int N = BB * LL;
    for (int idx = blockIdx.x * NTH + threadIdx.x; idx < N; idx += gridDim.x * NTH) {
        const int t  = idx & (LL - 1);
        const int b  = idx >> 15;              // LL = 2^15
        const int k0 = t >> 5;                 // RT = 32
        float g = 0.0f;
        #pragma unroll
        for (int dk = 4; dk >= 0; --dk) {
            const int k = k0 - dk;
            const int d = t - (k << 5);        // = (t&31) + 32*dk >= 0
            if (k >= 0 && k < NTILES && d < GPT)
                g += part[((size_t)b * NTILES + k) * SLOT + d];
        }
        const float m = g * groupWeight(t);
        s1 += m * m;
    }
    const int NS = BB * NTILES;
    for (int idx = blockIdx.x * NTH + threadIdx.x; idx < NS; idx += gridDim.x * NTH) {
        s2 += part[(size_t)idx * SLOT + GPT];
    }
    #pragma unroll
    for (int o = 32; o > 0; o >>= 1) {
        s1 += __shfl_down(s1, o, 64);
        s2 += __shfl_down(s2, o, 64);
    }
    if ((threadIdx.x & 63) == 0) { redA[threadIdx.x >> 6] = s1; redB[threadIdx.x >> 6] = s2; }
    __syncthreads();
    if (threadIdx.x == 0) {
        part2[blockIdx.x * 2 + 0] = redA[0] + redA[1] + redA[2] + redA[3];
        part2[blockIdx.x * 2 + 1] = redB[0] + redB[1] + redB[2] + redB[3];
    }
}

__global__ __launch_bounds__(NTH) void tc_final(const float* __restrict__ part2,
                                                float* __restrict__ out) {
    __shared__ float redA[NTH / 64], redB[NTH / 64];
    float s1 = 0.0f, s2 = 0.0f;
    for (int i = threadIdx.x; i < P2_BLOCKS; i += NTH) {
        s1 += part2[i * 2 + 0];
        s2 += part2[i * 2 + 1];
    }
    #pragma unroll
    for (int o = 32; o > 0; o >>= 1) {
        s1 += __shfl_down(s1, o, 64);
        s2 += __shfl_down(s2, o, 64);
    }
    if ((threadIdx.x & 63) == 0) { redA[threadIdx.x >> 6] = s1; redB[threadIdx.x >> 6] = s2; }
    __syncthreads();
    if (threadIdx.x == 0) {
        const float scale = (float)(0.1 / ((double)BB * (double)LL));
        out[0] = (redB[0] + redB[1] + redB[2] + redB[3]
                - (redA[0] + redA[1] + redA[2] + redA[3])) * scale;
    }
}

extern "C" void kernel_launch(void* const* d_in, const int* in_sizes, int n_in,
                              void* d_out, int out_size, void* d_ws, size_t ws_size,
                              hipStream_t stream) {
    const float* in = (const float*)d_in[0];
    float* part  = (float*)d_ws;                          // BB*NTILES*SLOT floats ~ 10.5 MB
    float* part2 = part + (size_t)BB * NTILES * SLOT;     // P2_BLOCKS*2 floats
    float* out   = (float*)d_out;

    dim3 g1(NCHUNK, BB);
    tc_pass1<<<g1, NTH, 0, stream>>>(in, part);
    tc_pass2<<<P2_BLOCKS, NTH, 0, stream>>>(part, part2);
    tc_final<<<1, NTH, 0, stream>>>(part2, out);
}

// Round 3
// 346.346 us; speedup vs baseline: 1.0275x; 1.0275x over previous
//
#include <hip/hip_runtime.h>

// Problem constants (match reference setup_inputs)
#define BB 16
#define TT 32641
#define EE 128
#define LL (TT + EE - 1)             // 32768 = 2^15 groups
#define RT 32                        // rows per tile (16 KB LDS)
#define NTILES ((TT + RT - 1) / RT)  // 1021 tiles per batch
#define GPT (RT + EE - 1)            // 159 group partials per tile
#define SLOT 160                     // stride: 159 G-partials + 1 Qw slot
#define NTH 256
#define CHUNK 8                      // tiles per block (pipelined)
#define NCHUNK ((NTILES + CHUNK - 1) / CHUNK)  // 128
#define P2_BLOCKS 2048               // was 256: 1 wave/SIMD was latency-bound floor

typedef float vf4 __attribute__((ext_vector_type(4)));

// c(t) = |{(i,j): i+j==t, 0<=i<TT, 0<=j<EE}|  (TT >= EE)
__device__ __forceinline__ float groupWeight(int t) {
    int c = min(min(t + 1, EE), LL - t);
    return 1.0f / (float)c;
}

// Raw barrier that does NOT drain vmcnt (unlike __syncthreads, which the
// compiler lowers to s_waitcnt vmcnt(0) lgkmcnt(0) + s_barrier). lgkmcnt(0)
// first so this wave's LDS writes/reads are complete before crossing; the
// "memory" clobber pins compiler ordering of LDS accesses around it.
#define LGKM_BARRIER() asm volatile("s_waitcnt lgkmcnt(0)\n\ts_barrier" ::: "memory")

// Issue nontemporal float4 loads for tile `ktile` into r0..r3 (guarded for
// the single partial tail tile, k = NTILES-1, nrows = 1).
#define ISSUE_LOADS(ktile)                                                         \
    do {                                                                           \
        const int _rr = (ktile) * RT;                                              \
        const vf4* __restrict__ _src = (const vf4*)(inb + (size_t)_rr * EE);       \
        const int _nvec = min(RT, TT - _rr) * (EE / 4);                            \
        if (_nvec == RT * (EE / 4)) {                                              \
            r0 = __builtin_nontemporal_load(&_src[tid + 0 * NTH]);                 \
            r1 = __builtin_nontemporal_load(&_src[tid + 1 * NTH]);                 \
            r2 = __builtin_nontemporal_load(&_src[tid + 2 * NTH]);                 \
            r3 = __builtin_nontemporal_load(&_src[tid + 3 * NTH]);                 \
        } else {                                                                   \
            if (tid + 0 * NTH < _nvec) r0 = __builtin_nontemporal_load(&_src[tid + 0 * NTH]); \
            if (tid + 1 * NTH < _nvec) r1 = __builtin_nontemporal_load(&_src[tid + 1 * NTH]); \
            if (tid + 2 * NTH < _nvec) r2 = __builtin_nontemporal_load(&_src[tid + 2 * NTH]); \
            if (tid + 3 * NTH < _nvec) r3 = __builtin_nontemporal_load(&_src[tid + 3 * NTH]); \
        }                                                                          \
    } while (0)

// Pass 1, pipelined: each block owns CHUNK consecutive tiles of one batch.
// Steady state per tile: regs->LDS (counted vmcnt waits only), raw barrier,
// issue next tile's loads (HBM latency hides under Phase B), diagonal
// compute, raw barrier. vmcnt is never drained to 0 inside the loop.
// R2: sched_barrier(0) after the prefetch issue was removed — order-pinning
// defeats the compiler scheduler (m141 lesson); suspected cause of the
// 346->356 noise-level regression.
__global__ __launch_bounds__(NTH, 8) void tc_pass1(const float* __restrict__ in,
                                                   float* __restrict__ part) {
    __shared__ float lsum[RT * EE];        // 16 KB, single buffer
    __shared__ float red[NTH / 64];
    const int tid = threadIdx.x;
    const int c   = (NCHUNK - 1) - blockIdx.x;   // reversed chunk order (R7)
    const int b   = (BB - 1) - blockIdx.y;       // reversed batch order (R7)
    const int k0  = c * CHUNK;
    const int ntile = min(CHUNK, NTILES - k0);

    vf4* __restrict__ ldst = (vf4*)lsum;
    const float* __restrict__ inb = in + (size_t)b * TT * EE;

    vf4 r0 = {0.f, 0.f, 0.f, 0.f}, r1 = r0, r2 = r0, r3 = r0;

    // prologue: issue loads for the first tile
    ISSUE_LOADS(k0);

    for (int t = 0; t < ntile; ++t) {
        const int k     = k0 + t;
        const int rrow  = k * RT;
        const int nrows = min(RT, TT - rrow);
        const int nvec  = nrows * (EE / 4);

        // staged regs -> LDS; compiler inserts counted s_waitcnt vmcnt(N)
        // per register, so newer prefetch loads stay in flight.
        if (nvec == RT * (EE / 4)) {
            ldst[tid + 0 * NTH] = r0;
            ldst[tid + 1 * NTH] = r1;
            ldst[tid + 2 * NTH] = r2;
            ldst[tid + 3 * NTH] = r3;
        } else {
            if (tid + 0 * NTH < nvec) ldst[tid + 0 * NTH] = r0;
            if (tid + 1 * NTH < nvec) ldst[tid + 1 * NTH] = r1;
            if (tid + 2 * NTH < nvec) ldst[tid + 2 * NTH] = r2;
            if (tid + 3 * NTH < nvec) ldst[tid + 3 * NTH] = r3;
        }
        LGKM_BARRIER();   // tile visible to all waves; vmcnt NOT drained

        // issue next tile's loads now: their latency hides under Phase B
        if (t + 1 < ntile) ISSUE_LOADS(k + 1);

        // Phase B: lane d walks anti-diagonal d: lsum[i*EE + (d-i)],
        // consecutive lanes -> consecutive LDS addresses -> conflict-free
        // (bank = (d-i) mod 32 at fixed i: 2-way over 64 lanes = free).
        float* __restrict__ base = part + ((size_t)b * NTILES + k) * SLOT;
        float qw = 0.0f;
        if (tid < GPT) {
            const int d   = tid;
            const int ilo = max(0, d - (EE - 1));
            const int ihi = min(nrows - 1, d);
            float g = 0.0f, q = 0.0f;
            for (int i = ilo; i <= ihi; ++i) {
                float x = lsum[i * EE + (d - i)];
                g += x;
                q += x * x;
            }
            base[d] = g;                       // zero when loop empty
            if (ihi >= ilo) qw = q * groupWeight(rrow + d);  // NaN guard for t >= LL
        }

        // block-reduce qw -> slot GPT (non-atomic)
        #pragma unroll
        for (int o = 32; o > 0; o >>= 1) qw += __shfl_down(qw, o, 64);
        if ((tid & 63) == 0) red[tid >> 6] = qw;
        // Doubles as "all lsum reads done" barrier: each wave's qw depends on
        // its ds_reads, and lgkmcnt(0) runs before s_barrier.
        LGKM_BARRIER();
        if (tid == 0) base[GPT] = red[0] + red[1] + red[2] + red[3];
        // tid 0's red[] read is ordered before the NEXT iteration's red[]
        // writes by the post-write barrier at the top of the next iteration.
    }
}

// Pass 2: S1 = sum over (b,t) of (G(b,t)*w(t))^2 from <=5 tile partials;
//         S2 = sum of per-tile w*q slots. Non-atomic block partials.
// R2: 2048 blocks (was 256 = 1 wave/SIMD, latency-bound on the 5-point
// gather). N = BB*LL = 524288 = exactly one element per thread now.
__global__ __launch_bounds__(NTH) void tc_pass2(const float* __restrict__ part,
                                                float* __restrict__ part2) {
    __shared__ float redA[NTH / 64], redB[NTH / 64];
    float s1 = 0.0f, s2 = 0.0f;
    const int N = BB * LL;
    for (int idx = blockIdx.x * NTH + threadIdx.x; idx < N; idx += gridDim.x * NTH) {
        const int t  = idx & (LL - 1);
        const int b  = idx >> 15;              // LL = 2^15
        const int k0 = t >> 5;                 // RT = 32
        float g = 0.0f;
        #pragma unroll
        for (int dk = 4; dk >= 0; --dk) {
            const int k = k0 - dk;
            const int d = t - (k << 5);        // = (t&31) + 32*dk >= 0
            if (k >= 0 && k < NTILES && d < GPT)
                g += part[((size_t)b * NTILES + k) * SLOT + d];
        }
        const float m = g * groupWeight(t);
        s1 += m * m;
    }
    const int NS = BB * NTILES;
    for (int idx = blockIdx.x * NTH + threadIdx.x; idx < NS; idx += gridDim.x * NTH) {
        s2 += part[(size_t)idx * SLOT + GPT];
    }
    #pragma unroll
    for (int o = 32; o > 0; o >>= 1) {
        s1 += __shfl_down(s1, o, 64);
        s2 += __shfl_down(s2, o, 64);
    }
    if ((threadIdx.x & 63) == 0) { redA[threadIdx.x >> 6] = s1; redB[threadIdx.x >> 6] = s2; }
    __syncthreads();
    if (threadIdx.x == 0) {
        part2[blockIdx.x * 2 + 0] = redA[0] + redA[1] + redA[2] + redA[3];
        part2[blockIdx.x * 2 + 1] = redB[0] + redB[1] + redB[2] + redB[3];
    }
}

__global__ __launch_bounds__(NTH) void tc_final(const float* __restrict__ part2,
                                                float* __restrict__ out) {
    __shared__ float redA[NTH / 64], redB[NTH / 64];
    float s1 = 0.0f, s2 = 0.0f;
    for (int i = threadIdx.x; i < P2_BLOCKS; i += NTH) {
        s1 += part2[i * 2 + 0];
        s2 += part2[i * 2 + 1];
    }
    #pragma unroll
    for (int o = 32; o > 0; o >>= 1) {
        s1 += __shfl_down(s1, o, 64);
        s2 += __shfl_down(s2, o, 64);
    }
    if ((threadIdx.x & 63) == 0) { redA[threadIdx.x >> 6] = s1; redB[threadIdx.x >> 6] = s2; }
    __syncthreads();
    if (threadIdx.x == 0) {
        const float scale = (float)(0.1 / ((double)BB * (double)LL));
        out[0] = (redB[0] + redB[1] + redB[2] + redB[3]
                - (redA[0] + redA[1] + redA[2] + redA[3])) * scale;
    }
}

extern "C" void kernel_launch(void* const* d_in, const int* in_sizes, int n_in,
                              void* d_out, int out_size, void* d_ws, size_t ws_size,
                              hipStream_t stream) {
    const float* in = (const float*)d_in[0];
    float* part  = (float*)d_ws;                          // BB*NTILES*SLOT floats ~ 10.5 MB
    float* part2 = part + (size_t)BB * NTILES * SLOT;     // P2_BLOCKS*2 floats (16 KB)
    float* out   = (float*)d_out;

    dim3 g1(NCHUNK, BB);
    tc_pass1<<<g1, NTH, 0, stream>>>(in, part);
    tc_pass2<<<P2_BLOCKS, NTH, 0, stream>>>(part, part2);
    tc_final<<<1, NTH, 0, stream>>>(part2, out);
}

// Round 4
// 340.174 us; speedup vs baseline: 1.0462x; 1.0181x over previous
//
#include <hip/hip_runtime.h>

// Problem constants (match reference setup_inputs)
#define BB 16
#define TT 32641
#define EE 128
#define LL (TT + EE - 1)            // 32768 = 2^15 groups
#define SPAN 64                     // rows per wave
#define NSPAN ((TT + SPAN - 1) / SPAN)     // 511 spans per batch (last has 1 row)
#define WPB 4                       // waves per block
#define NTH 256
#define P1_BLOCKS ((BB * NSPAN) / WPB)     // 16*511/4 = 2044 (exact)
#define P2_BLOCKS 2048
#define PLANES 4                    // partial planes: 2*(span&1)+window
#define P2N (BB * LL)

typedef float vf2 __attribute__((ext_vector_type(2)));

// c(t) = |{(i,j): i+j==t, 0<=i<TT, 0<=j<EE}|  (TT >= EE)
__device__ __forceinline__ float groupWeight(int t) {
    int c = min(min(t + 1, EE), LL - t);
    return 1.0f / (float)c;
}

// ---------------------------------------------------------------------------
// Pass 1 (R4 rewrite): barrier-free, LDS-free diagonal accumulation.
// One wave streams SPAN contiguous rows [a, a+R) of one batch. Lane m owns
// ring offsets o = {2m, 2m+1} of two 128-wide t-windows:
//   window g covers t in [a+128g, a+128g+128), g in {0,1}  (R<=64 => Δ<=189)
// Row s element j contributes to Δ = s+j; dest lane m = (Δ&127)>>1.
//  even s (h=s/2):      slot.x <- src[(m-h)&63].x, slot.y <- src[(m-h)&63].y,
//                       window1 iff m < h  (both slots)
//  odd  s (h=(s+1)/2):  slot.x <- src[(m-h)&63].y   (window1 iff m   < h)
//                       slot.y <- src[(m-h+1)&63].x (window1 iff m+1 < h)
// Retirement: write both windows to partial planes; plane = 2*(span&1)+g is
// a bijection over the <=3 real writers of any t => no atomics, no zeroing,
// fully deterministic. Pass 2 sums the 3 valid planes per (b,t).
// ---------------------------------------------------------------------------
__global__ __launch_bounds__(NTH, 8) void tc_pass1(const float* __restrict__ in,
                                                   float* __restrict__ PG,
                                                   float* __restrict__ PQ) {
    const int lane = threadIdx.x & 63;
    const int W    = blockIdx.x * WPB + (threadIdx.x >> 6);  // global wave id
    const int b    = W / NSPAN;
    const int span = W - b * NSPAN;
    const int a    = span * SPAN;
    const int R    = min(SPAN, TT - a);          // 64, except last span = 1

    const float* __restrict__ rowp = in + ((size_t)b * TT + a) * EE + 2 * lane;

    float gc0 = 0.f, gc1 = 0.f, gn0 = 0.f, gn1 = 0.f;   // G cur/next window
    float qc0 = 0.f, qc1 = 0.f, qn0 = 0.f, qn1 = 0.f;   // Q cur/next window

    #define PE(v, s) do {                                                     \
        const int h = (s) >> 1;                                               \
        float rx = __shfl((v).x, (lane - h) & 63, 64);                        \
        float ry = __shfl((v).y, (lane - h) & 63, 64);                        \
        const bool wr = lane < h;                                             \
        float sx = rx * rx, sy = ry * ry;                                     \
        float n0 = wr ? rx : 0.0f, n1 = wr ? ry : 0.0f;                       \
        float m0 = wr ? sx : 0.0f, m1 = wr ? sy : 0.0f;                       \
        gc0 += rx - n0; gn0 += n0; gc1 += ry - n1; gn1 += n1;                 \
        qc0 += sx - m0; qn0 += m0; qc1 += sy - m1; qn1 += m1;                 \
    } while (0)

    #define PO(v, s) do {                                                     \
        const int h = ((s) + 1) >> 1;                                         \
        float rx = __shfl((v).y, (lane - h) & 63, 64);     /* -> slot .x */   \
        float ry = __shfl((v).x, (lane - h + 1) & 63, 64); /* -> slot .y */   \
        const bool wx = lane < h;                                             \
        const bool wy = (lane + 1) < h;                                       \
        float sx = rx * rx, sy = ry * ry;                                     \
        float n0 = wx ? rx : 0.0f, n1 = wy ? ry : 0.0f;                       \
        float m0 = wx ? sx : 0.0f, m1 = wy ? sy : 0.0f;                       \
        gc0 += rx - n0; gn0 += n0; gc1 += ry - n1; gn1 += n1;                 \
        qc0 += sx - m0; qn0 += m0; qc1 += sy - m1; qn1 += m1;                 \
    } while (0)

    // 2-row software pipeline: load rows s+2, s+3 while processing s, s+1.
    vf2 v0 = __builtin_nontemporal_load((const vf2*)rowp);
    vf2 v1 = (R > 1) ? __builtin_nontemporal_load((const vf2*)(rowp + EE))
                     : vf2{0.f, 0.f};
    int s = 0;
    for (; s + 2 < R; s += 2) {
        vf2 n0 = __builtin_nontemporal_load((const vf2*)(rowp + (size_t)(s + 2) * EE));
        vf2 n1 = (s + 3 < R)
                   ? __builtin_nontemporal_load((const vf2*)(rowp + (size_t)(s + 3) * EE))
                   : vf2{0.f, 0.f};
        PE(v0, s);
        PO(v1, s + 1);
        v0 = n0; v1 = n1;
    }
    PE(v0, s);
    if (s + 1 < R) PO(v1, s + 1);

    // Retirement: window0 always fully in-bounds (a+127 <= LL-1); window1
    // needs a t < LL guard (populated offsets are provably <= 62 there).
    const int p0 = 2 * (span & 1);
    float* __restrict__ pg0 = PG + ((size_t)b * PLANES + p0) * LL;
    float* __restrict__ pq0 = PQ + ((size_t)b * PLANES + p0) * LL;
    const int o  = 2 * lane;
    pg0[a + o] = gc0;  pg0[a + o + 1] = gc1;
    pq0[a + o] = qc0;  pq0[a + o + 1] = qc1;

    float* __restrict__ pg1 = pg0 + LL;          // plane p0+1
    float* __restrict__ pq1 = pq0 + LL;
    const int t1 = a + 128 + o;
    if (t1 + 1 < LL) {
        pg1[t1] = gn0; pg1[t1 + 1] = gn1;
        pq1[t1] = qn0; pq1[t1 + 1] = qn1;
    } else if (t1 < LL) {
        pg1[t1] = gn0; pq1[t1] = qn0;
    }
    #undef PE
    #undef PO
}

// ---------------------------------------------------------------------------
// Pass 2: for each (b,t) sum the 3 valid partial planes -> G, Q; accumulate
// s1 = sum (G*w)^2 and s2 = sum Q*w. Non-atomic block partials.
// Valid writers for t (w0 = t>>6): span w0 win0 (plane 2*(w0&1), iff w0<=510),
// span w0-1 win0 (plane 2*((w0-1)&1), iff w0>=1), span w0-2 win1
// (plane 2*(w0&1)+1, iff w0>=2). span w0-3's win1 is provably zero.
// ---------------------------------------------------------------------------
__global__ __launch_bounds__(NTH) void tc_pass2(const float* __restrict__ PG,
                                                const float* __restrict__ PQ,
                                                float* __restrict__ part2) {
    __shared__ float redA[NTH / 64], redB[NTH / 64];
    float s1 = 0.0f, s2 = 0.0f;
    for (int idx = blockIdx.x * NTH + threadIdx.x; idx < P2N; idx += gridDim.x * NTH) {
        const int t  = idx & (LL - 1);
        const int b  = idx >> 15;                 // LL = 2^15
        const int w0 = t >> 6;                    // SPAN = 64
        const size_t base = (size_t)b * PLANES * LL + t;
        float g = 0.0f, q = 0.0f;
        if (w0 <= NSPAN - 1) {
            const size_t off = base + (size_t)(2 * (w0 & 1)) * LL;
            g += PG[off]; q += PQ[off];
        }
        if (w0 >= 1) {
            const size_t off = base + (size_t)(2 * ((w0 - 1) & 1)) * LL;
            g += PG[off]; q += PQ[off];
        }
        if (w0 >= 2) {
            const size_t off = base + (size_t)(2 * (w0 & 1) + 1) * LL;
            g += PG[off]; q += PQ[off];
        }
        const float fw = groupWeight(t);
        const float m  = g * fw;
        s1 += m * m;
        s2 += q * fw;
    }
    #pragma unroll
    for (int o = 32; o > 0; o >>= 1) {
        s1 += __shfl_down(s1, o, 64);
        s2 += __shfl_down(s2, o, 64);
    }
    if ((threadIdx.x & 63) == 0) { redA[threadIdx.x >> 6] = s1; redB[threadIdx.x >> 6] = s2; }
    __syncthreads();
    if (threadIdx.x == 0) {
        part2[blockIdx.x * 2 + 0] = redA[0] + redA[1] + redA[2] + redA[3];
        part2[blockIdx.x * 2 + 1] = redB[0] + redB[1] + redB[2] + redB[3];
    }
}

__global__ __launch_bounds__(NTH) void tc_final(const float* __restrict__ part2,
                                                float* __restrict__ out) {
    __shared__ float redA[NTH / 64], redB[NTH / 64];
    float s1 = 0.0f, s2 = 0.0f;
    for (int i = threadIdx.x; i < P2_BLOCKS; i += NTH) {
        s1 += part2[i * 2 + 0];
        s2 += part2[i * 2 + 1];
    }
    #pragma unroll
    for (int o = 32; o > 0; o >>= 1) {
        s1 += __shfl_down(s1, o, 64);
        s2 += __shfl_down(s2, o, 64);
    }
    if ((threadIdx.x & 63) == 0) { redA[threadIdx.x >> 6] = s1; redB[threadIdx.x >> 6] = s2; }
    __syncthreads();
    if (threadIdx.x == 0) {
        const float scale = (float)(0.1 / ((double)BB * (double)LL));
        out[0] = (redB[0] + redB[1] + redB[2] + redB[3]
                - (redA[0] + redA[1] + redA[2] + redA[3])) * scale;
    }
}

extern "C" void kernel_launch(void* const* d_in, const int* in_sizes, int n_in,
                              void* d_out, int out_size, void* d_ws, size_t ws_size,
                              hipStream_t stream) {
    const float* in = (const float*)d_in[0];
    float* PG    = (float*)d_ws;                          // BB*4*LL floats = 8 MB
    float* PQ    = PG + (size_t)BB * PLANES * LL;         // 8 MB
    float* part2 = PQ + (size_t)BB * PLANES * LL;         // P2_BLOCKS*2 floats
    float* out   = (float*)d_out;

    tc_pass1<<<P1_BLOCKS, NTH, 0, stream>>>(in, PG, PQ);
    tc_pass2<<<P2_BLOCKS, NTH, 0, stream>>>(PG, PQ, part2);
    tc_final<<<1, NTH, 0, stream>>>(part2, out);
}